// Round 4
// baseline (473.479 us; speedup 1.0000x reference)
//
#include <hip/hip_runtime.h>
#include <hip/hip_bf16.h>

#define T_DIM 4096
#define B_DIM 32
#define H_DIM 128
#define M_DIM (T_DIM * B_DIM)        // 131072 GEMM rows (t*B + b)
#define G_DIM 512                    // 4*H gate columns
#define TBH   ((long)M_DIM * H_DIM)  // 16777216 output elements for `outputs`

typedef __attribute__((ext_vector_type(8))) short short8;    // 8 bf16 = 4 VGPRs (MFMA A/B frag)
typedef __attribute__((ext_vector_type(4))) short short4v;   // 4 bf16 = 8 bytes
typedef __attribute__((ext_vector_type(4))) float floatx4;   // MFMA C/D frag

__device__ __forceinline__ unsigned short f2bf_rne(float x) {
    union { float f; unsigned int u; } v; v.f = x;
    unsigned int r = v.u + 0x7FFFu + ((v.u >> 16) & 1u);   // round-nearest-even
    return (unsigned short)(r >> 16);
}
__device__ __forceinline__ unsigned short f2bf_rh(float x) {
    union { float f; unsigned int u; } v; v.f = x;
    return (unsigned short)((v.u + 0x8000u) >> 16);        // round-half-up (cheap, ~unbiased)
}
__device__ __forceinline__ float sigm(float x) {
    return __builtin_amdgcn_rcpf(1.0f + __expf(-x));       // saturates cleanly at 0/1
}
__device__ __forceinline__ float tanh_fast(float x) {
    float e = __expf(-2.0f * __builtin_fabsf(x));          // in (0,1]
    float t = (1.0f - e) * __builtin_amdgcn_rcpf(1.0f + e);
    return __builtin_copysignf(t, x);
}

// Fused prep, fully parallel grid (4176 blocks):
//  blocks [0,4096):    hhT[g][b] = h0[b,:]·W_hh[g,:] + b_ih[g] + b_hh[g]
//                      one wave per (b,g): coalesced float2 row reads + shuffle reduce
//  blocks [4096,4160): W_ih fp32 -> bf16 (RNE) into Wb
//  blocks [4160,4176): transpose c0,noise -> [h][b] for vectorized epilogue loads
__global__ __launch_bounds__(256) void prep(
    const float* __restrict__ h0, const float* __restrict__ c0,
    const float* __restrict__ noise, const float* __restrict__ W_ih,
    const float* __restrict__ W_hh, const float* __restrict__ b_ih,
    const float* __restrict__ b_hh, unsigned short* __restrict__ Wb,
    float* __restrict__ hhT, float* __restrict__ c0T, float* __restrict__ nzT)
{
    const int tid = threadIdx.x;
    const int bid = blockIdx.x;
    if (bid < 4096) {
        const int wave = tid >> 6, lane = tid & 63;
        const int pair = bid * 4 + wave;      // 0..16383
        const int b = pair >> 9;              // 0..31
        const int g = pair & 511;             // 0..511
        const int k = lane * 2;
        const float2 wv = *(const float2*)(W_hh + g * 128 + k);
        const float2 hv = *(const float2*)(h0 + b * 128 + k);
        float s = wv.x * hv.x + wv.y * hv.y;
        #pragma unroll
        for (int m = 32; m >= 1; m >>= 1) s += __shfl_xor(s, m, 64);
        if (lane == 0) hhT[g * 32 + b] = s + b_ih[g] + b_hh[g];
    } else if (bid < 4160) {
        const int e = ((bid - 4096) * 256 + tid) * 4;   // 64*256*4 = 65536 elements
        float4 f = *(const float4*)(W_ih + e);
        short4v s;
        s[0] = (short)f2bf_rne(f.x); s[1] = (short)f2bf_rne(f.y);
        s[2] = (short)f2bf_rne(f.z); s[3] = (short)f2bf_rne(f.w);
        *(short4v*)(Wb + e) = s;
    } else {
        const int i = (bid - 4160) * 256 + tid;         // 16*256 = 4096 elements
        const int b = i >> 7, h = i & 127;
        c0T[h * 32 + b] = c0[i];
        nzT[h * 32 + b] = noise[i];
    }
}

__device__ __forceinline__ short8 cvt_frag(const float* p) {
    // 8 consecutive fp32 -> bf16x8 fragment (round-half-up)
    float4 f0 = *(const float4*)(p);
    float4 f1 = *(const float4*)(p + 4);
    short8 a;
    a[0] = (short)f2bf_rh(f0.x); a[1] = (short)f2bf_rh(f0.y);
    a[2] = (short)f2bf_rh(f0.z); a[3] = (short)f2bf_rh(f0.w);
    a[4] = (short)f2bf_rh(f1.x); a[5] = (short)f2bf_rh(f1.y);
    a[6] = (short)f2bf_rh(f1.z); a[7] = (short)f2bf_rh(f1.w);
    return a;
}

// Per block: 32 rows x 512 gate cols GEMM (K=128) + fused LSTM-cell epilogue.
// Wave w owns h-cols [w*32, w*32+32) across all 4 gates -> epilogue is wave-local.
// All [b]-indexed side inputs are pre-transposed to [col][b] so init/epilogue
// loads are float4 (b = mt*16 + q*4 + r is contiguous in r).
__global__ __launch_bounds__(256, 6) void lstm_main(
    const float* __restrict__ X,              // [M,128] fp32 input rows
    const unsigned short* __restrict__ W,     // [512,128] bf16 W_ih (pre-converted, B^T layout)
    const float* __restrict__ hhT,            // [512,32] fp32: recurrent term + biases, transposed
    const float* __restrict__ c0T,            // [128,32] fp32 transposed
    const float* __restrict__ nzT,            // [128,32] fp32 transposed
    float* __restrict__ out)                  // fp32: outputs[M*128], h_last[4096], c_last[4096]
{
    const int tid  = threadIdx.x;
    const int w    = tid >> 6;       // wave 0..3
    const int lane = tid & 63;
    const int q    = lane >> 4;      // quad 0..3
    const int lr   = lane & 15;
    const int m_base = blockIdx.x << 5;   // 32 rows per block, 32-aligned

    // Accumulators seeded with hhT (fuses recurrent term + biases).
    // C/D layout: col = lane&15, row = q*4 + reg  ->  b = mt*16 + q*4 + r.
    floatx4 acc[2][8];
    #pragma unroll
    for (int mt = 0; mt < 2; ++mt)
        #pragma unroll
        for (int gt = 0; gt < 4; ++gt)
            #pragma unroll
            for (int hc = 0; hc < 2; ++hc) {
                const int col = gt * 128 + w * 32 + hc * 16 + lr;
                acc[mt][gt * 2 + hc] = *(const floatx4*)(hhT + col * 32 + mt * 16 + q * 4);
            }

    // GEMM: gates[m,col] += X[m,:]·W[col,:]
    const float* xr0 = X + (long)(m_base +      lr) * 128;
    const float* xr1 = X + (long)(m_base + 16 + lr) * 128;
    #pragma unroll
    for (int kt = 0; kt < 4; ++kt) {
        // A frag: lane holds A[m = mt*16+lr][k = kt*32 + q*8 + 0..8), cvt fp32->bf16
        short8 a0 = cvt_frag(xr0 + kt * 32 + q * 8);
        short8 a1 = cvt_frag(xr1 + kt * 32 + q * 8);
        #pragma unroll
        for (int gt = 0; gt < 4; ++gt)
            #pragma unroll
            for (int hc = 0; hc < 2; ++hc) {
                const int col = gt * 128 + w * 32 + hc * 16 + lr;
                // B frag: lane holds B[k = kt*32 + q*8 + 0..8)][n = lr] = W[col][k]
                short8 bf = *(const short8*)(W + col * 128 + kt * 32 + q * 8);
                const int n = gt * 2 + hc;
                acc[0][n] = __builtin_amdgcn_mfma_f32_16x16x32_bf16(a0, bf, acc[0][n], 0, 0, 0);
                acc[1][n] = __builtin_amdgcn_mfma_f32_16x16x32_bf16(a1, bf, acc[1][n], 0, 0, 0);
            }
    }

    // Epilogue: per (mt,hc) the 4 regs span b = mt*16+q*4 .. +3 -> float4 side loads
    const bool last = (m_base == M_DIM - 32);   // whole last block is t = T-1
    #pragma unroll
    for (int mt = 0; mt < 2; ++mt) {
        floatx4 cv[2], nv[2];
        #pragma unroll
        for (int hc = 0; hc < 2; ++hc) {
            const int hcol = w * 32 + hc * 16 + lr;
            cv[hc] = *(const floatx4*)(c0T + hcol * 32 + mt * 16 + q * 4);
            nv[hc] = *(const floatx4*)(nzT + hcol * 32 + mt * 16 + q * 4);
        }
        #pragma unroll
        for (int r = 0; r < 4; ++r) {
            const int row = m_base + mt * 16 + q * 4 + r;
            const int b   = mt * 16 + q * 4 + r;
            #pragma unroll
            for (int hc = 0; hc < 2; ++hc) {
                const int hcol = w * 32 + hc * 16 + lr;
                const float gi = sigm(acc[mt][0 + hc][r]);
                const float gf = sigm(acc[mt][2 + hc][r]);
                const float gg = tanh_fast(acc[mt][4 + hc][r]);
                const float go = sigm(acc[mt][6 + hc][r]);
                const float cc = gf * cv[hc][r] + gi * gg;
                const float hv = go * tanh_fast(cc) + nv[hc][r];
                out[(long)row * 128 + hcol] = hv;
                if (last) {
                    out[TBH +        b * 128 + hcol] = hv;
                    out[TBH + 4096 + b * 128 + hcol] = cc;
                }
            }
        }
    }
}

extern "C" void kernel_launch(void* const* d_in, const int* in_sizes, int n_in,
                              void* d_out, int out_size, void* d_ws, size_t ws_size,
                              hipStream_t stream) {
    const float* X     = (const float*)d_in[0];
    const float* h0    = (const float*)d_in[1];
    const float* c0    = (const float*)d_in[2];
    const float* noise = (const float*)d_in[3];
    const float* W_ih  = (const float*)d_in[4];
    const float* W_hh  = (const float*)d_in[5];
    const float* b_ih  = (const float*)d_in[6];
    const float* b_hh  = (const float*)d_in[7];

    char* ws = (char*)d_ws;
    unsigned short* Wb  = (unsigned short*)(ws);             // 512*128 bf16 = 131072 B
    float*          hhT = (float*)(ws + 131072);             // 512*32 fp32  =  65536 B
    float*          c0T = (float*)(ws + 196608);             // 128*32 fp32  =  16384 B
    float*          nzT = (float*)(ws + 212992);             // 128*32 fp32  =  16384 B
    float* out = (float*)d_out;

    prep<<<dim3(4176), dim3(256), 0, stream>>>(h0, c0, noise, W_ih, W_hh, b_ih, b_hh,
                                               Wb, hhT, c0T, nzT);
    lstm_main<<<dim3(M_DIM / 32), dim3(256), 0, stream>>>(X, Wb, hhT, c0T, nzT, out);
}

// Round 5
// 245.129 us; speedup vs baseline: 1.9316x; 1.9316x over previous
//
#include <hip/hip_runtime.h>
#include <hip/hip_bf16.h>

#define T_DIM 4096
#define B_DIM 32
#define H_DIM 128
#define M_DIM (T_DIM * B_DIM)        // 131072 GEMM rows (t*B + b)
#define G_DIM 512                    // 4*H gate columns
#define TBH   ((long)M_DIM * H_DIM)  // 16777216 output elements for `outputs`

typedef __attribute__((ext_vector_type(8))) short short8;    // 8 bf16 = 4 VGPRs (MFMA A/B frag)
typedef __attribute__((ext_vector_type(4))) short short4v;   // 4 bf16 = 8 bytes
typedef __attribute__((ext_vector_type(4))) float floatx4;   // MFMA C/D frag

__device__ __forceinline__ unsigned short f2bf_rne(float x) {
    union { float f; unsigned int u; } v; v.f = x;
    unsigned int r = v.u + 0x7FFFu + ((v.u >> 16) & 1u);   // round-nearest-even
    return (unsigned short)(r >> 16);
}
__device__ __forceinline__ unsigned short f2bf_rh(float x) {
    union { float f; unsigned int u; } v; v.f = x;
    return (unsigned short)((v.u + 0x8000u) >> 16);        // round-half-up (cheap, ~unbiased)
}
__device__ __forceinline__ float sigm(float x) {
    return __builtin_amdgcn_rcpf(1.0f + __expf(-x));       // saturates cleanly at 0/1
}
__device__ __forceinline__ float tanh_fast(float x) {
    float e = __expf(-2.0f * __builtin_fabsf(x));          // in (0,1]
    float t = (1.0f - e) * __builtin_amdgcn_rcpf(1.0f + e);
    return __builtin_copysignf(t, x);
}

// Fused prep, fully parallel grid (4176 blocks):
//  blocks [0,4096):    hhT[g][b] = h0[b,:]·W_hh[g,:] + b_ih[g] + b_hh[g]
//                      one wave per (b,g): coalesced float2 row reads + shuffle reduce
//  blocks [4096,4160): W_ih fp32 -> bf16 (RNE) into Wb
//  blocks [4160,4176): transpose c0,noise -> [h][b] for vectorized epilogue loads
__global__ __launch_bounds__(256) void prep(
    const float* __restrict__ h0, const float* __restrict__ c0,
    const float* __restrict__ noise, const float* __restrict__ W_ih,
    const float* __restrict__ W_hh, const float* __restrict__ b_ih,
    const float* __restrict__ b_hh, unsigned short* __restrict__ Wb,
    float* __restrict__ hhT, float* __restrict__ c0T, float* __restrict__ nzT)
{
    const int tid = threadIdx.x;
    const int bid = blockIdx.x;
    if (bid < 4096) {
        const int wave = tid >> 6, lane = tid & 63;
        const int pair = bid * 4 + wave;      // 0..16383
        const int b = pair >> 9;              // 0..31
        const int g = pair & 511;             // 0..511
        const int k = lane * 2;
        const float2 wv = *(const float2*)(W_hh + g * 128 + k);
        const float2 hv = *(const float2*)(h0 + b * 128 + k);
        float s = wv.x * hv.x + wv.y * hv.y;
        #pragma unroll
        for (int m = 32; m >= 1; m >>= 1) s += __shfl_xor(s, m, 64);
        if (lane == 0) hhT[g * 32 + b] = s + b_ih[g] + b_hh[g];
    } else if (bid < 4160) {
        const int e = ((bid - 4096) * 256 + tid) * 4;   // 64*256*4 = 65536 elements
        float4 f = *(const float4*)(W_ih + e);
        short4v s;
        s[0] = (short)f2bf_rne(f.x); s[1] = (short)f2bf_rne(f.y);
        s[2] = (short)f2bf_rne(f.z); s[3] = (short)f2bf_rne(f.w);
        *(short4v*)(Wb + e) = s;
    } else {
        const int i = (bid - 4160) * 256 + tid;         // 16*256 = 4096 elements
        const int b = i >> 7, h = i & 127;
        c0T[h * 32 + b] = c0[i];
        nzT[h * 32 + b] = noise[i];
    }
}

__device__ __forceinline__ short8 cvt_frag(const float* p) {
    // 8 consecutive fp32 -> bf16x8 fragment (round-half-up)
    float4 f0 = *(const float4*)(p);
    float4 f1 = *(const float4*)(p + 4);
    short8 a;
    a[0] = (short)f2bf_rh(f0.x); a[1] = (short)f2bf_rh(f0.y);
    a[2] = (short)f2bf_rh(f0.z); a[3] = (short)f2bf_rh(f0.w);
    a[4] = (short)f2bf_rh(f1.x); a[5] = (short)f2bf_rh(f1.y);
    a[6] = (short)f2bf_rh(f1.z); a[7] = (short)f2bf_rh(f1.w);
    return a;
}

// Per block: 32 rows x 512 gate cols GEMM (K=128) + fused LSTM-cell epilogue.
// Wave w owns h-cols [w*32, w*32+32) across all 4 gates -> epilogue is wave-local.
// All [b]-indexed side inputs are pre-transposed to [col][b] so init/epilogue
// loads are float4 (b = mt*16 + q*4 + r is contiguous in r).
// launch_bounds(256,4): 128-VGPR budget. (256,6) forced an 85-VGPR budget and
// SPILLED the 64-VGPR accumulator array -> 1.1 GB scratch traffic (round 4).
__global__ __launch_bounds__(256, 4) void lstm_main(
    const float* __restrict__ X,              // [M,128] fp32 input rows
    const unsigned short* __restrict__ W,     // [512,128] bf16 W_ih (pre-converted, B^T layout)
    const float* __restrict__ hhT,            // [512,32] fp32: recurrent term + biases, transposed
    const float* __restrict__ c0T,            // [128,32] fp32 transposed
    const float* __restrict__ nzT,            // [128,32] fp32 transposed
    float* __restrict__ out)                  // fp32: outputs[M*128], h_last[4096], c_last[4096]
{
    const int tid  = threadIdx.x;
    const int w    = tid >> 6;       // wave 0..3
    const int lane = tid & 63;
    const int q    = lane >> 4;      // quad 0..3
    const int lr   = lane & 15;
    const int m_base = blockIdx.x << 5;   // 32 rows per block, 32-aligned

    // Accumulators seeded with hhT (fuses recurrent term + biases).
    // C/D layout: col = lane&15, row = q*4 + reg  ->  b = mt*16 + q*4 + r.
    floatx4 acc[2][8];
    #pragma unroll
    for (int mt = 0; mt < 2; ++mt)
        #pragma unroll
        for (int gt = 0; gt < 4; ++gt)
            #pragma unroll
            for (int hc = 0; hc < 2; ++hc) {
                const int col = gt * 128 + w * 32 + hc * 16 + lr;
                acc[mt][gt * 2 + hc] = *(const floatx4*)(hhT + col * 32 + mt * 16 + q * 4);
            }

    // GEMM: gates[m,col] += X[m,:]·W[col,:]
    const float* xr0 = X + (long)(m_base +      lr) * 128;
    const float* xr1 = X + (long)(m_base + 16 + lr) * 128;
    #pragma unroll
    for (int kt = 0; kt < 4; ++kt) {
        // A frag: lane holds A[m = mt*16+lr][k = kt*32 + q*8 + 0..8), cvt fp32->bf16
        short8 a0 = cvt_frag(xr0 + kt * 32 + q * 8);
        short8 a1 = cvt_frag(xr1 + kt * 32 + q * 8);
        #pragma unroll
        for (int gt = 0; gt < 4; ++gt)
            #pragma unroll
            for (int hc = 0; hc < 2; ++hc) {
                const int col = gt * 128 + w * 32 + hc * 16 + lr;
                // B frag: lane holds B[k = kt*32 + q*8 + 0..8)][n = lr] = W[col][k]
                short8 bf = *(const short8*)(W + col * 128 + kt * 32 + q * 8);
                const int n = gt * 2 + hc;
                acc[0][n] = __builtin_amdgcn_mfma_f32_16x16x32_bf16(a0, bf, acc[0][n], 0, 0, 0);
                acc[1][n] = __builtin_amdgcn_mfma_f32_16x16x32_bf16(a1, bf, acc[1][n], 0, 0, 0);
            }
    }

    // Epilogue: per (mt,hc) the 4 regs span b = mt*16+q*4 .. +3 -> float4 side loads
    const bool last = (m_base == M_DIM - 32);   // whole last block is t = T-1
    #pragma unroll
    for (int mt = 0; mt < 2; ++mt) {
        floatx4 cv[2], nv[2];
        #pragma unroll
        for (int hc = 0; hc < 2; ++hc) {
            const int hcol = w * 32 + hc * 16 + lr;
            cv[hc] = *(const floatx4*)(c0T + hcol * 32 + mt * 16 + q * 4);
            nv[hc] = *(const floatx4*)(nzT + hcol * 32 + mt * 16 + q * 4);
        }
        #pragma unroll
        for (int r = 0; r < 4; ++r) {
            const int row = m_base + mt * 16 + q * 4 + r;
            const int b   = mt * 16 + q * 4 + r;
            #pragma unroll
            for (int hc = 0; hc < 2; ++hc) {
                const int hcol = w * 32 + hc * 16 + lr;
                const float gi = sigm(acc[mt][0 + hc][r]);
                const float gf = sigm(acc[mt][2 + hc][r]);
                const float gg = tanh_fast(acc[mt][4 + hc][r]);
                const float go = sigm(acc[mt][6 + hc][r]);
                const float cc = gf * cv[hc][r] + gi * gg;
                const float hv = go * tanh_fast(cc) + nv[hc][r];
                out[(long)row * 128 + hcol] = hv;
                if (last) {
                    out[TBH +        b * 128 + hcol] = hv;
                    out[TBH + 4096 + b * 128 + hcol] = cc;
                }
            }
        }
    }
}

extern "C" void kernel_launch(void* const* d_in, const int* in_sizes, int n_in,
                              void* d_out, int out_size, void* d_ws, size_t ws_size,
                              hipStream_t stream) {
    const float* X     = (const float*)d_in[0];
    const float* h0    = (const float*)d_in[1];
    const float* c0    = (const float*)d_in[2];
    const float* noise = (const float*)d_in[3];
    const float* W_ih  = (const float*)d_in[4];
    const float* W_hh  = (const float*)d_in[5];
    const float* b_ih  = (const float*)d_in[6];
    const float* b_hh  = (const float*)d_in[7];

    char* ws = (char*)d_ws;
    unsigned short* Wb  = (unsigned short*)(ws);             // 512*128 bf16 = 131072 B
    float*          hhT = (float*)(ws + 131072);             // 512*32 fp32  =  65536 B
    float*          c0T = (float*)(ws + 196608);             // 128*32 fp32  =  16384 B
    float*          nzT = (float*)(ws + 212992);             // 128*32 fp32  =  16384 B
    float* out = (float*)d_out;

    prep<<<dim3(4176), dim3(256), 0, stream>>>(h0, c0, noise, W_ih, W_hh, b_ih, b_hh,
                                               Wb, hhT, c0T, nzT);
    lstm_main<<<dim3(M_DIM / 32), dim3(256), 0, stream>>>(X, Wb, hhT, c0T, nzT, out);
}